// Round 14
// baseline (208.409 us; speedup 1.0000x reference)
//
#include <hip/hip_runtime.h>
#include <math.h>

#define B_SZ   16384
#define D_DIM  256
#define E_NUM  8
#define O_DIM  128
#define CTXW   32
#define H1     64

// out layout (f32):
#define OFF_RW   2097152
#define OFF_IDX  2129920
#define OFF_NP   2162688
#define OFF_NA   2162696
#define OFF_NE   2162704

// ws layout:
//  int  wsi[0..7]    : slot-0 cursors (per expert, grows from front of list)
//  int  wsi[8..15]   : slot-1 cursors (per expert, grows from back of list)
//  f32  wsf[256 + copy*24 + j] : 64 stat copies; j: 0..7 cnt, 8..15 rsum, 16..23 wsum
//  int  wsi[2048 + e*16384 ...]: per-expert arena; slot0 entries at [base..],
//                                slot1 entries at [B_SZ-1-base..] (value = row)
// First 8192 BYTES zeroed via hipMemsetAsync before score_k.
#define WS_STATS 256
#define WS_LIST  2048

// ---------------- K1: encoder + scorer + UCB + top2 + list build (f64) ----------------
// 16 rows/block (1024 blocks), 4 rows/wave. x staged in LDS PRE-CONVERTED to
// f64 (exact) — per-row f64 fma order identical to all passing rounds.
__global__ __launch_bounds__(256) void score_k(
    const float* __restrict__ x,
    const float* __restrict__ W1, const float* __restrict__ b1,
    const float* __restrict__ W2, const float* __restrict__ b2,
    const float* __restrict__ S1, const float* __restrict__ sb1,
    const float* __restrict__ S2, const float* __restrict__ sb2,
    const float* __restrict__ er, const int* __restrict__ pulls,
    const int* __restrict__ tsel,
    float* __restrict__ out, int* __restrict__ wsi)
{
    __shared__ double xs[16][D_DIM];   // 32 KB (f64-staged x)
    __shared__ double hs[16][H1];      // 8 KB
    __shared__ double cs[16][CTXW];    // 4 KB
    __shared__ double tss[16][CTXW];   // 4 KB
    __shared__ double ucb[16][E_NUM];  // 1 KB
    __shared__ int    se[32];

    const int t = threadIdx.x, lane = t & 63, wv = t >> 6;
    const int row0 = blockIdx.x * 16;

    // stage 16 rows of x, converting f32 -> f64 once (exact)
    const float4* xsrc = (const float4*)(x + (size_t)row0 * D_DIM);
    #pragma unroll
    for (int i = 0; i < 4; ++i) {
        float4 v = xsrc[t + i * 256];
        double* dst = &xs[0][0] + (size_t)(t + i * 256) * 4;
        dst[0] = (double)v.x; dst[1] = (double)v.y;
        dst[2] = (double)v.z; dst[3] = (double)v.w;
    }
    __syncthreads();

    // ---- h = relu(x@W1+b1): lane = unit, 4 rows per wave, 2 accs/row ----
    const int rb = wv * 4;
    {
        double a00 = (double)b1[lane], a01 = 0.0;
        double a10 = a00, a11 = 0.0;
        double a20 = a00, a21 = 0.0;
        double a30 = a00, a31 = 0.0;
        #pragma unroll 4
        for (int d = 0; d < D_DIM; d += 2) {
            double2 p0 = *(const double2*)&xs[rb + 0][d];
            double2 p1 = *(const double2*)&xs[rb + 1][d];
            double2 p2 = *(const double2*)&xs[rb + 2][d];
            double2 p3 = *(const double2*)&xs[rb + 3][d];
            double wa = (double)W1[d * H1 + lane];
            double wb = (double)W1[(d + 1) * H1 + lane];
            a00 = fma(p0.x, wa, a00); a01 = fma(p0.y, wb, a01);
            a10 = fma(p1.x, wa, a10); a11 = fma(p1.y, wb, a11);
            a20 = fma(p2.x, wa, a20); a21 = fma(p2.y, wb, a21);
            a30 = fma(p3.x, wa, a30); a31 = fma(p3.y, wb, a31);
        }
        double h0 = a00 + a01, h1 = a10 + a11, h2 = a20 + a21, h3 = a30 + a31;
        hs[rb + 0][lane] = h0 > 0.0 ? h0 : 0.0;
        hs[rb + 1][lane] = h1 > 0.0 ? h1 : 0.0;
        hs[rb + 2][lane] = h2 > 0.0 ? h2 : 0.0;
        hs[rb + 3][lane] = h3 > 0.0 ? h3 : 0.0;
    }
    __syncthreads();

    // ---- context = tanh(h@W2+b2): unit = lane&31, half handles 2 rows ----
    {
        const int unit = lane & 31, half = lane >> 5;
        const int ra = rb + half * 2;
        double c0 = (double)b2[unit], c1 = c0;
        #pragma unroll 4
        for (int k = 0; k < H1; ++k) {
            double w2v = (double)W2[k * CTXW + unit];
            c0 = fma(hs[ra][k], w2v, c0);
            c1 = fma(hs[ra + 1][k], w2v, c1);
        }
        cs[ra][unit] = tanh(c0);
        cs[ra + 1][unit] = tanh(c1);
    }
    __syncthreads();

    // ---- tmid = relu(context@S1+sb1) ----
    {
        const int unit = lane & 31, half = lane >> 5;
        const int ra = rb + half * 2;
        double a0 = (double)sb1[unit], a1 = a0;
        #pragma unroll 4
        for (int k = 0; k < CTXW; ++k) {
            double s1v = (double)S1[k * CTXW + unit];
            a0 = fma(cs[ra][k], s1v, a0);
            a1 = fma(cs[ra + 1][k], s1v, a1);
        }
        tss[ra][unit]     = a0 > 0.0 ? a0 : 0.0;
        tss[ra + 1][unit] = a1 > 0.0 ? a1 : 0.0;
    }
    __syncthreads();

    // ---- scores + UCB: lanes<32, e = lane&7, row = rb + (lane>>3) ----
    if (lane < 32) {
        const int e = lane & 7, r = rb + (lane >> 3);
        double a = (double)sb2[e];
        #pragma unroll 4
        for (int k = 0; k < CTXW; ++k)
            a = fma(tss[r][k], (double)S2[k * E_NUM + e], a);
        double pf = (double)pulls[e];
        double sp = pf < 1.0 ? 1.0 : pf;
        double explo = 0.1 * sqrt(log((double)(*tsel)) / sp);
        double avg = pf > 0.0 ? (double)er[e] / sp : 0.0;
        ucb[r][e] = a + avg + explo;
    }
    __syncthreads();

    // ---- top2 + softmax + emit: threads 0..15, one row each ----
    if (t < 16) {
        double u[E_NUM];
        #pragma unroll
        for (int e = 0; e < E_NUM; ++e) u[e] = ucb[t][e];
        int i0 = 0; double v0 = u[0];
        #pragma unroll
        for (int e = 1; e < E_NUM; ++e) if (u[e] > v0) { v0 = u[e]; i0 = e; }
        int i1 = -1; double v1 = -1.0e300;
        #pragma unroll
        for (int e = 0; e < E_NUM; ++e) {
            if (e == i0) continue;
            if (u[e] > v1) { v1 = u[e]; i1 = e; }
        }
        double exd = exp(v1 - v0);
        double w0 = 1.0 / (1.0 + exd), w1 = exd / (1.0 + exd);
        int row = row0 + t;
        out[OFF_RW  + row * 2]     = (float)w0;
        out[OFF_RW  + row * 2 + 1] = (float)w1;
        out[OFF_IDX + row * 2]     = (float)i0;
        out[OFF_IDX + row * 2 + 1] = (float)i1;
        se[t * 2]     = i0;
        se[t * 2 + 1] = i1;
    }
    __syncthreads();

    // ---- block-aggregated list append: 16 threads, one per (expert, slot) ----
    if (t < 16) {
        const int e = t & 7, slot = t >> 3;
        int cntl = 0;
        for (int j = slot; j < 32; j += 2) cntl += (se[j] == e);
        if (cntl) {
            int base = atomicAdd(&wsi[slot * 8 + e], cntl);
            int k = 0;
            if (slot == 0) {
                for (int j = 0; j < 32; j += 2)
                    if (se[j] == e)
                        wsi[WS_LIST + e * B_SZ + base + (k++)] = row0 + (j >> 1);
            } else {
                for (int j = 1; j < 32; j += 2)
                    if (se[j] == e)
                        wsi[WS_LIST + e * B_SZ + (B_SZ - 1 - base - (k++))] = row0 + (j >> 1);
            }
        }
    }
}

// ---------------- K2: grouped expert GEMM + losses + stats, per slot ----------------
// 32-row chunks. SLOT 0: pred = w*sel (plain store).  SLOT 1: pred += w*sel
// (plain RMW — race-free: one entry per (row,slot); slot0 completes first).
template <int SLOT>
__global__ __launch_bounds__(256) void expert_k(
    const float* __restrict__ x, const float* __restrict__ tgt,
    const float* __restrict__ We, const float* __restrict__ be,
    float* out, int* __restrict__ wsi, float* __restrict__ wsf)
{
    const int e = blockIdx.x >> 9, chunk = blockIdx.x & 511;
    const int cnt = wsi[SLOT * 8 + e];
    const int base = chunk * 32;
    if (base >= cnt) return;

    __shared__ float xsl[32][68];      // 8.7 KB
    __shared__ float wes[64][O_DIM];   // 32 KB
    __shared__ int   rowid[32];
    __shared__ float wsl[32];
    __shared__ float be_sh[O_DIM];

    const int t = threadIdx.x;
    if (t < 32) {
        bool ok = (base + t) < cnt;
        int row = -1;
        if (ok) {
            int idx = (SLOT == 0) ? (base + t) : (B_SZ - 1 - (base + t));
            row = wsi[WS_LIST + e * B_SZ + idx];
        }
        rowid[t] = row;
        wsl[t]   = ok ? out[OFF_RW + row * 2 + SLOT] : 0.f;
    }
    if (t < O_DIM) be_sh[t] = be[e * O_DIM + t];

    float acc[4][4];
    #pragma unroll
    for (int r = 0; r < 4; ++r)
        #pragma unroll
        for (int j = 0; j < 4; ++j) acc[r][j] = 0.f;

    const int tx = t & 31, ty = t >> 5;   // ty 0..7 -> rows ty*4..ty*4+3
    const int o4 = tx * 4;

    for (int k0 = 0; k0 < 4; ++k0) {
        __syncthreads();
        // stage We chunk [64 k][128 o] — contiguous 32 KB
        const float4* wsrc = (const float4*)(We + ((size_t)e * D_DIM + k0 * 64) * O_DIM);
        #pragma unroll
        for (int i = 0; i < 8; ++i)
            ((float4*)wes)[t + i * 256] = wsrc[t + i * 256];
        // stage x rows [32 r][64 k]
        {
            int r = t >> 3, seg = t & 7;
            int rr = rowid[r] < 0 ? 0 : rowid[r];
            const float* xsr = x + (size_t)rr * D_DIM + k0 * 64 + seg * 8;
            *(float4*)&xsl[r][seg * 8]     = *(const float4*)(xsr);
            *(float4*)&xsl[r][seg * 8 + 4] = *(const float4*)(xsr + 4);
        }
        __syncthreads();
        // compute
        #pragma unroll 4
        for (int kq = 0; kq < 16; ++kq) {
            float4 w0 = *(float4*)&wes[kq * 4 + 0][o4];
            float4 w1 = *(float4*)&wes[kq * 4 + 1][o4];
            float4 w2 = *(float4*)&wes[kq * 4 + 2][o4];
            float4 w3 = *(float4*)&wes[kq * 4 + 3][o4];
            #pragma unroll
            for (int r = 0; r < 4; ++r) {
                float4 xv = *(float4*)&xsl[ty * 4 + r][kq * 4];
                acc[r][0] = fmaf(xv.x, w0.x, acc[r][0]);
                acc[r][1] = fmaf(xv.x, w0.y, acc[r][1]);
                acc[r][2] = fmaf(xv.x, w0.z, acc[r][2]);
                acc[r][3] = fmaf(xv.x, w0.w, acc[r][3]);
                acc[r][0] = fmaf(xv.y, w1.x, acc[r][0]);
                acc[r][1] = fmaf(xv.y, w1.y, acc[r][1]);
                acc[r][2] = fmaf(xv.y, w1.z, acc[r][2]);
                acc[r][3] = fmaf(xv.y, w1.w, acc[r][3]);
                acc[r][0] = fmaf(xv.z, w2.x, acc[r][0]);
                acc[r][1] = fmaf(xv.z, w2.y, acc[r][1]);
                acc[r][2] = fmaf(xv.z, w2.z, acc[r][2]);
                acc[r][3] = fmaf(xv.z, w2.w, acc[r][3]);
                acc[r][0] = fmaf(xv.w, w3.x, acc[r][0]);
                acc[r][1] = fmaf(xv.w, w3.y, acc[r][1]);
                acc[r][2] = fmaf(xv.w, w3.z, acc[r][2]);
                acc[r][3] = fmaf(xv.w, w3.w, acc[r][3]);
            }
        }
    }

    // epilogue: bias, predictions (store / RMW-add), per-(row,slot) loss
    float cntl = 0.f, rsl = 0.f, wsuml = 0.f;
    #pragma unroll
    for (int r = 0; r < 4; ++r) {
        int li = ty * 4 + r;
        int row = rowid[li];
        bool valid = row >= 0;
        float w = wsl[li];
        float4 tg = make_float4(0.f, 0.f, 0.f, 0.f);
        if (valid) tg = *(const float4*)(tgt + (size_t)row * O_DIM + o4);
        float cf0 = acc[r][0] + be_sh[o4 + 0];
        float cf1 = acc[r][1] + be_sh[o4 + 1];
        float cf2 = acc[r][2] + be_sh[o4 + 2];
        float cf3 = acc[r][3] + be_sh[o4 + 3];
        float d0 = cf0 - tg.x, d1 = cf1 - tg.y, d2 = cf2 - tg.z, d3 = cf3 - tg.w;
        float lpr = d0 * d0 + d1 * d1 + d2 * d2 + d3 * d3;
        if (valid) {
            float* pr = out + (size_t)row * O_DIM + o4;
            if (SLOT == 0) {
                float4 v = make_float4(w * cf0, w * cf1, w * cf2, w * cf3);
                *(float4*)pr = v;
            } else {
                float4 p = *(const float4*)pr;
                p.x += w * cf0; p.y += w * cf1; p.z += w * cf2; p.w += w * cf3;
                *(float4*)pr = p;
            }
        }
        #pragma unroll
        for (int off = 1; off < 32; off <<= 1)
            lpr += __shfl_xor(lpr, off, 64);
        if (tx == 0 && valid) {
            cntl += 1.f;
            rsl  += -(lpr * (1.0f / 128.0f));
            wsuml += w;
        }
    }
    if (tx == 0) {
        int cp = WS_STATS + (blockIdx.x & 63) * 24;
        if (cntl > 0.f) {
            atomicAdd(&wsf[cp + e], cntl);
            atomicAdd(&wsf[cp + 8 + e], rsl);
            atomicAdd(&wsf[cp + 16 + e], wsuml);
        }
    }
}

// ---------------- K3: finalize stats ----------------
__global__ void final_k(const float* __restrict__ er,
                        const float* __restrict__ ema,
                        const int* __restrict__ pulls,
                        const float* __restrict__ wsf,
                        float* __restrict__ out)
{
    int e = threadIdx.x;
    if (e < E_NUM) {
        double c = 0.0, rs = 0.0, wsum = 0.0;
        for (int cp = 0; cp < 64; ++cp) {
            c    += (double)wsf[WS_STATS + cp * 24 + e];
            rs   += (double)wsf[WS_STATS + cp * 24 + 8 + e];
            wsum += (double)wsf[WS_STATS + cp * 24 + 16 + e];
        }
        double pf = (double)pulls[e];
        double npl = pf + c;
        double ntr = (double)er[e] + rs;
        double sp = npl < 1.0 ? 1.0 : npl;
        double navg = npl > 0.0 ? ntr / sp : 0.0;
        double prob = wsum / (double)B_SZ;
        double nema = 0.99 * (double)ema[e] + 0.01 * prob;
        out[OFF_NP + e] = (float)npl;
        out[OFF_NA + e] = (float)navg;
        out[OFF_NE + e] = (float)nema;
    }
}

extern "C" void kernel_launch(void* const* d_in, const int* in_sizes, int n_in,
                              void* d_out, int out_size, void* d_ws, size_t ws_size,
                              hipStream_t stream) {
    const float* x    = (const float*)d_in[0];
    const float* tgt  = (const float*)d_in[1];
    const float* W1   = (const float*)d_in[2];
    const float* b1   = (const float*)d_in[3];
    const float* W2   = (const float*)d_in[4];
    const float* b2   = (const float*)d_in[5];
    const float* S1   = (const float*)d_in[6];
    const float* sb1  = (const float*)d_in[7];
    const float* S2   = (const float*)d_in[8];
    const float* sb2  = (const float*)d_in[9];
    const float* We   = (const float*)d_in[10];
    const float* be   = (const float*)d_in[11];
    const float* erw  = (const float*)d_in[12];
    const float* ema  = (const float*)d_in[13];
    const int*   pulls = (const int*)d_in[14];
    const int*   tsel  = (const int*)d_in[15];
    float* out = (float*)d_out;
    float* wsf = (float*)d_ws;
    int*   wsi = (int*)d_ws;

    // zero cursors (64 B) + stat copies (floats 256..1792) in one async memset
    hipMemsetAsync(d_ws, 0, 8192, stream);
    score_k<<<B_SZ / 16, 256, 0, stream>>>(
        x, W1, b1, W2, b2, S1, sb1, S2, sb2, erw, pulls, tsel, out, wsi);
    expert_k<0><<<E_NUM * 512, 256, 0, stream>>>(x, tgt, We, be, out, wsi, wsf);
    expert_k<1><<<E_NUM * 512, 256, 0, stream>>>(x, tgt, We, be, out, wsi, wsf);
    final_k<<<1, 64, 0, stream>>>(erw, ema, pulls, wsf, out);
}

// Round 15
// 196.454 us; speedup vs baseline: 1.0609x; 1.0609x over previous
//
#include <hip/hip_runtime.h>
#include <math.h>

#define B_SZ   16384
#define D_DIM  256
#define E_NUM  8
#define O_DIM  128
#define CTXW   32
#define H1     64

// out layout (f32):
#define OFF_RW   2097152
#define OFF_IDX  2129920
#define OFF_NP   2162688
#define OFF_NA   2162696
#define OFF_NE   2162704

// ws layout:
//  int  wsi[0..7]    : slot-0 cursors;  wsi[8..15]: slot-1 cursors
//  f32  wsf[256 + copy*24 + j] : 64 stat copies; j: 0..7 cnt, 8..15 rsum, 16..23 wsum
//  int  wsi[2048 + e*16384 ...]: per-expert arena; slot0 from front, slot1 from back
//  f32  wsf[WS_TMP ...]        : slot-1 prediction tmp [B,128] (fused path only)
// First 8192 BYTES zeroed via hipMemsetAsync before score_k.
#define WS_STATS 256
#define WS_LIST  2048
#define WS_TMP   1048576   // float offset = 4 MB byte offset
#define WS_NEED  ((size_t)(WS_TMP + B_SZ * O_DIM) * 4)

// ---------------- K1: encoder + scorer + UCB + top2 + list build (f64) ----------------
// Round-13 proven config: 16 rows/block, 4 rows/wave, f32-staged x.
__global__ __launch_bounds__(256) void score_k(
    const float* __restrict__ x,
    const float* __restrict__ W1, const float* __restrict__ b1,
    const float* __restrict__ W2, const float* __restrict__ b2,
    const float* __restrict__ S1, const float* __restrict__ sb1,
    const float* __restrict__ S2, const float* __restrict__ sb2,
    const float* __restrict__ er, const int* __restrict__ pulls,
    const int* __restrict__ tsel,
    float* __restrict__ out, int* __restrict__ wsi)
{
    __shared__ float  xs[16][D_DIM];   // 16 KB
    __shared__ double hs[16][H1];      // 8 KB
    __shared__ double cs[16][CTXW];    // 4 KB
    __shared__ double tss[16][CTXW];   // 4 KB
    __shared__ double ucb[16][E_NUM];  // 1 KB
    __shared__ int    se[32];

    const int t = threadIdx.x, lane = t & 63, wv = t >> 6;
    const int row0 = blockIdx.x * 16;

    const float4* xsrc = (const float4*)(x + (size_t)row0 * D_DIM);
    #pragma unroll
    for (int i = 0; i < 4; ++i)
        ((float4*)xs)[t + i * 256] = xsrc[t + i * 256];
    __syncthreads();

    // ---- h = relu(x@W1+b1): lane = unit, 4 rows per wave, 2 accs/row ----
    const int rb = wv * 4;
    {
        double a00 = (double)b1[lane], a01 = 0.0;
        double a10 = a00, a11 = 0.0;
        double a20 = a00, a21 = 0.0;
        double a30 = a00, a31 = 0.0;
        #pragma unroll 4
        for (int d = 0; d < D_DIM; d += 2) {
            float2 p0 = *(const float2*)&xs[rb + 0][d];
            float2 p1 = *(const float2*)&xs[rb + 1][d];
            float2 p2 = *(const float2*)&xs[rb + 2][d];
            float2 p3 = *(const float2*)&xs[rb + 3][d];
            double wa = (double)W1[d * H1 + lane];
            double wb = (double)W1[(d + 1) * H1 + lane];
            a00 = fma((double)p0.x, wa, a00); a01 = fma((double)p0.y, wb, a01);
            a10 = fma((double)p1.x, wa, a10); a11 = fma((double)p1.y, wb, a11);
            a20 = fma((double)p2.x, wa, a20); a21 = fma((double)p2.y, wb, a21);
            a30 = fma((double)p3.x, wa, a30); a31 = fma((double)p3.y, wb, a31);
        }
        double h0 = a00 + a01, h1 = a10 + a11, h2 = a20 + a21, h3 = a30 + a31;
        hs[rb + 0][lane] = h0 > 0.0 ? h0 : 0.0;
        hs[rb + 1][lane] = h1 > 0.0 ? h1 : 0.0;
        hs[rb + 2][lane] = h2 > 0.0 ? h2 : 0.0;
        hs[rb + 3][lane] = h3 > 0.0 ? h3 : 0.0;
    }
    __syncthreads();

    // ---- context = tanh(h@W2+b2) ----
    {
        const int unit = lane & 31, half = lane >> 5;
        const int ra = rb + half * 2;
        double c0 = (double)b2[unit], c1 = c0;
        #pragma unroll 4
        for (int k = 0; k < H1; ++k) {
            double w2v = (double)W2[k * CTXW + unit];
            c0 = fma(hs[ra][k], w2v, c0);
            c1 = fma(hs[ra + 1][k], w2v, c1);
        }
        cs[ra][unit] = tanh(c0);
        cs[ra + 1][unit] = tanh(c1);
    }
    __syncthreads();

    // ---- tmid = relu(context@S1+sb1) ----
    {
        const int unit = lane & 31, half = lane >> 5;
        const int ra = rb + half * 2;
        double a0 = (double)sb1[unit], a1 = a0;
        #pragma unroll 4
        for (int k = 0; k < CTXW; ++k) {
            double s1v = (double)S1[k * CTXW + unit];
            a0 = fma(cs[ra][k], s1v, a0);
            a1 = fma(cs[ra + 1][k], s1v, a1);
        }
        tss[ra][unit]     = a0 > 0.0 ? a0 : 0.0;
        tss[ra + 1][unit] = a1 > 0.0 ? a1 : 0.0;
    }
    __syncthreads();

    // ---- scores + UCB ----
    if (lane < 32) {
        const int e = lane & 7, r = rb + (lane >> 3);
        double a = (double)sb2[e];
        #pragma unroll 4
        for (int k = 0; k < CTXW; ++k)
            a = fma(tss[r][k], (double)S2[k * E_NUM + e], a);
        double pf = (double)pulls[e];
        double sp = pf < 1.0 ? 1.0 : pf;
        double explo = 0.1 * sqrt(log((double)(*tsel)) / sp);
        double avg = pf > 0.0 ? (double)er[e] / sp : 0.0;
        ucb[r][e] = a + avg + explo;
    }
    __syncthreads();

    // ---- top2 + softmax + emit ----
    if (t < 16) {
        double u[E_NUM];
        #pragma unroll
        for (int e = 0; e < E_NUM; ++e) u[e] = ucb[t][e];
        int i0 = 0; double v0 = u[0];
        #pragma unroll
        for (int e = 1; e < E_NUM; ++e) if (u[e] > v0) { v0 = u[e]; i0 = e; }
        int i1 = -1; double v1 = -1.0e300;
        #pragma unroll
        for (int e = 0; e < E_NUM; ++e) {
            if (e == i0) continue;
            if (u[e] > v1) { v1 = u[e]; i1 = e; }
        }
        double exd = exp(v1 - v0);
        double w0 = 1.0 / (1.0 + exd), w1 = exd / (1.0 + exd);
        int row = row0 + t;
        out[OFF_RW  + row * 2]     = (float)w0;
        out[OFF_RW  + row * 2 + 1] = (float)w1;
        out[OFF_IDX + row * 2]     = (float)i0;
        out[OFF_IDX + row * 2 + 1] = (float)i1;
        se[t * 2]     = i0;
        se[t * 2 + 1] = i1;
    }
    __syncthreads();

    // ---- block-aggregated list append: 16 threads, one per (expert, slot) ----
    if (t < 16) {
        const int e = t & 7, slot = t >> 3;
        int cntl = 0;
        for (int j = slot; j < 32; j += 2) cntl += (se[j] == e);
        if (cntl) {
            int base = atomicAdd(&wsi[slot * 8 + e], cntl);
            int k = 0;
            if (slot == 0) {
                for (int j = 0; j < 32; j += 2)
                    if (se[j] == e)
                        wsi[WS_LIST + e * B_SZ + base + (k++)] = row0 + (j >> 1);
            } else {
                for (int j = 1; j < 32; j += 2)
                    if (se[j] == e)
                        wsi[WS_LIST + e * B_SZ + (B_SZ - 1 - base - (k++))] = row0 + (j >> 1);
            }
        }
    }
}

// ---------------- K2 core: grouped expert GEMM + losses + stats ----------------
// FUSED=1: one launch covers both slots; slot1 writes w*sel to tmp (plain store).
// FUSED=0: per-slot launch; SLOTP fixes the slot; slot1 RMWs out (stream-ordered).
template <int FUSED, int SLOTP>
__global__ __launch_bounds__(256) void expert_k(
    const float* __restrict__ x, const float* __restrict__ tgt,
    const float* __restrict__ We, const float* __restrict__ be,
    float* out, int* __restrict__ wsi, float* __restrict__ wsf,
    float* __restrict__ tmp)
{
    const int slot = FUSED ? (blockIdx.x >> 12) : SLOTP;
    const int e = (blockIdx.x >> 9) & 7, chunk = blockIdx.x & 511;
    const int cnt = wsi[slot * 8 + e];
    const int base = chunk * 32;
    if (base >= cnt) return;

    __shared__ float xsl[32][68];      // 8.7 KB
    __shared__ float wes[64][O_DIM];   // 32 KB
    __shared__ int   rowid[32];
    __shared__ float wsl[32];
    __shared__ float be_sh[O_DIM];

    const int t = threadIdx.x;
    if (t < 32) {
        bool ok = (base + t) < cnt;
        int row = -1;
        if (ok) {
            int idx = (slot == 0) ? (base + t) : (B_SZ - 1 - (base + t));
            row = wsi[WS_LIST + e * B_SZ + idx];
        }
        rowid[t] = row;
        wsl[t]   = ok ? out[OFF_RW + row * 2 + slot] : 0.f;
    }
    if (t < O_DIM) be_sh[t] = be[e * O_DIM + t];

    float acc[4][4];
    #pragma unroll
    for (int r = 0; r < 4; ++r)
        #pragma unroll
        for (int j = 0; j < 4; ++j) acc[r][j] = 0.f;

    const int tx = t & 31, ty = t >> 5;
    const int o4 = tx * 4;

    for (int k0 = 0; k0 < 4; ++k0) {
        __syncthreads();
        const float4* wsrc = (const float4*)(We + ((size_t)e * D_DIM + k0 * 64) * O_DIM);
        #pragma unroll
        for (int i = 0; i < 8; ++i)
            ((float4*)wes)[t + i * 256] = wsrc[t + i * 256];
        {
            int r = t >> 3, seg = t & 7;
            int rr = rowid[r] < 0 ? 0 : rowid[r];
            const float* xsr = x + (size_t)rr * D_DIM + k0 * 64 + seg * 8;
            *(float4*)&xsl[r][seg * 8]     = *(const float4*)(xsr);
            *(float4*)&xsl[r][seg * 8 + 4] = *(const float4*)(xsr + 4);
        }
        __syncthreads();
        #pragma unroll 4
        for (int kq = 0; kq < 16; ++kq) {
            float4 w0 = *(float4*)&wes[kq * 4 + 0][o4];
            float4 w1 = *(float4*)&wes[kq * 4 + 1][o4];
            float4 w2 = *(float4*)&wes[kq * 4 + 2][o4];
            float4 w3 = *(float4*)&wes[kq * 4 + 3][o4];
            #pragma unroll
            for (int r = 0; r < 4; ++r) {
                float4 xv = *(float4*)&xsl[ty * 4 + r][kq * 4];
                acc[r][0] = fmaf(xv.x, w0.x, acc[r][0]);
                acc[r][1] = fmaf(xv.x, w0.y, acc[r][1]);
                acc[r][2] = fmaf(xv.x, w0.z, acc[r][2]);
                acc[r][3] = fmaf(xv.x, w0.w, acc[r][3]);
                acc[r][0] = fmaf(xv.y, w1.x, acc[r][0]);
                acc[r][1] = fmaf(xv.y, w1.y, acc[r][1]);
                acc[r][2] = fmaf(xv.y, w1.z, acc[r][2]);
                acc[r][3] = fmaf(xv.y, w1.w, acc[r][3]);
                acc[r][0] = fmaf(xv.z, w2.x, acc[r][0]);
                acc[r][1] = fmaf(xv.z, w2.y, acc[r][1]);
                acc[r][2] = fmaf(xv.z, w2.z, acc[r][2]);
                acc[r][3] = fmaf(xv.z, w2.w, acc[r][3]);
                acc[r][0] = fmaf(xv.w, w3.x, acc[r][0]);
                acc[r][1] = fmaf(xv.w, w3.y, acc[r][1]);
                acc[r][2] = fmaf(xv.w, w3.z, acc[r][2]);
                acc[r][3] = fmaf(xv.w, w3.w, acc[r][3]);
            }
        }
    }

    float cntl = 0.f, rsl = 0.f, wsuml = 0.f;
    #pragma unroll
    for (int r = 0; r < 4; ++r) {
        int li = ty * 4 + r;
        int row = rowid[li];
        bool valid = row >= 0;
        float w = wsl[li];
        float4 tg = make_float4(0.f, 0.f, 0.f, 0.f);
        if (valid) tg = *(const float4*)(tgt + (size_t)row * O_DIM + o4);
        float cf0 = acc[r][0] + be_sh[o4 + 0];
        float cf1 = acc[r][1] + be_sh[o4 + 1];
        float cf2 = acc[r][2] + be_sh[o4 + 2];
        float cf3 = acc[r][3] + be_sh[o4 + 3];
        float d0 = cf0 - tg.x, d1 = cf1 - tg.y, d2 = cf2 - tg.z, d3 = cf3 - tg.w;
        float lpr = d0 * d0 + d1 * d1 + d2 * d2 + d3 * d3;
        if (valid) {
            if (FUSED) {
                float* pr = (slot == 0 ? out : tmp) + (size_t)row * O_DIM + o4;
                *(float4*)pr = make_float4(w * cf0, w * cf1, w * cf2, w * cf3);
            } else {
                float* pr = out + (size_t)row * O_DIM + o4;
                if (SLOTP == 0) {
                    *(float4*)pr = make_float4(w * cf0, w * cf1, w * cf2, w * cf3);
                } else {
                    float4 p = *(const float4*)pr;
                    p.x += w * cf0; p.y += w * cf1; p.z += w * cf2; p.w += w * cf3;
                    *(float4*)pr = p;
                }
            }
        }
        #pragma unroll
        for (int off = 1; off < 32; off <<= 1)
            lpr += __shfl_xor(lpr, off, 64);
        if (tx == 0 && valid) {
            cntl += 1.f;
            rsl  += -(lpr * (1.0f / 128.0f));
            wsuml += w;
        }
    }
    if (tx == 0) {
        int cp = WS_STATS + (blockIdx.x & 63) * 24;
        if (cntl > 0.f) {
            atomicAdd(&wsf[cp + e], cntl);
            atomicAdd(&wsf[cp + 8 + e], rsl);
            atomicAdd(&wsf[cp + 16 + e], wsuml);
        }
    }
}

// ---------------- combine: pred += tmp (fused path only) ----------------
__global__ __launch_bounds__(256) void combine_k(float* out, const float* __restrict__ tmp) {
    int i = blockIdx.x * 256 + threadIdx.x;   // 2048 blocks x 256 = 524288 float4
    float4 p = ((const float4*)out)[i];
    float4 q = ((const float4*)tmp)[i];
    p.x += q.x; p.y += q.y; p.z += q.z; p.w += q.w;
    ((float4*)out)[i] = p;
}

// ---------------- K3: finalize stats ----------------
__global__ void final_k(const float* __restrict__ er,
                        const float* __restrict__ ema,
                        const int* __restrict__ pulls,
                        const float* __restrict__ wsf,
                        float* __restrict__ out)
{
    int e = threadIdx.x;
    if (e < E_NUM) {
        double c = 0.0, rs = 0.0, wsum = 0.0;
        for (int cp = 0; cp < 64; ++cp) {
            c    += (double)wsf[WS_STATS + cp * 24 + e];
            rs   += (double)wsf[WS_STATS + cp * 24 + 8 + e];
            wsum += (double)wsf[WS_STATS + cp * 24 + 16 + e];
        }
        double pf = (double)pulls[e];
        double npl = pf + c;
        double ntr = (double)er[e] + rs;
        double sp = npl < 1.0 ? 1.0 : npl;
        double navg = npl > 0.0 ? ntr / sp : 0.0;
        double prob = wsum / (double)B_SZ;
        double nema = 0.99 * (double)ema[e] + 0.01 * prob;
        out[OFF_NP + e] = (float)npl;
        out[OFF_NA + e] = (float)navg;
        out[OFF_NE + e] = (float)nema;
    }
}

extern "C" void kernel_launch(void* const* d_in, const int* in_sizes, int n_in,
                              void* d_out, int out_size, void* d_ws, size_t ws_size,
                              hipStream_t stream) {
    const float* x    = (const float*)d_in[0];
    const float* tgt  = (const float*)d_in[1];
    const float* W1   = (const float*)d_in[2];
    const float* b1   = (const float*)d_in[3];
    const float* W2   = (const float*)d_in[4];
    const float* b2   = (const float*)d_in[5];
    const float* S1   = (const float*)d_in[6];
    const float* sb1  = (const float*)d_in[7];
    const float* S2   = (const float*)d_in[8];
    const float* sb2  = (const float*)d_in[9];
    const float* We   = (const float*)d_in[10];
    const float* be   = (const float*)d_in[11];
    const float* erw  = (const float*)d_in[12];
    const float* ema  = (const float*)d_in[13];
    const int*   pulls = (const int*)d_in[14];
    const int*   tsel  = (const int*)d_in[15];
    float* out = (float*)d_out;
    float* wsf = (float*)d_ws;
    int*   wsi = (int*)d_ws;
    float* tmp = wsf + WS_TMP;

    hipMemsetAsync(d_ws, 0, 8192, stream);
    score_k<<<B_SZ / 16, 256, 0, stream>>>(
        x, W1, b1, W2, b2, S1, sb1, S2, sb2, erw, pulls, tsel, out, wsi);
    if (ws_size >= WS_NEED) {
        // fused: both slots in one launch; slot1 -> tmp; then combine
        expert_k<1, 0><<<2 * E_NUM * 512, 256, 0, stream>>>(
            x, tgt, We, be, out, wsi, wsf, tmp);
        combine_k<<<2048, 256, 0, stream>>>(out, tmp);
    } else {
        expert_k<0, 0><<<E_NUM * 512, 256, 0, stream>>>(
            x, tgt, We, be, out, wsi, wsf, tmp);
        expert_k<0, 1><<<E_NUM * 512, 256, 0, stream>>>(
            x, tgt, We, be, out, wsi, wsf, tmp);
    }
    final_k<<<1, 64, 0, stream>>>(erw, ema, pulls, wsf, out);
}

// Round 16
// 195.310 us; speedup vs baseline: 1.0671x; 1.0059x over previous
//
#include <hip/hip_runtime.h>
#include <math.h>

#define B_SZ   16384
#define D_DIM  256
#define E_NUM  8
#define O_DIM  128
#define CTXW   32
#define H1     64

// out layout (f32):
#define OFF_RW   2097152
#define OFF_IDX  2129920
#define OFF_NP   2162688
#define OFF_NA   2162696
#define OFF_NE   2162704

// ws layout:
//  int  wsi[0..7]    : slot-0 cursors;  wsi[8..15]: slot-1 cursors
//  f32  wsf[256 + copy*24 + j] : 64 stat copies; j: 0..7 cnt, 8..15 rsum, 16..23 wsum
//  int  wsi[2048 + e*16384 ...]: per-expert arena; slot0 from front, slot1 from back
//  f32  wsf[WS_TMP ...]        : slot-1 prediction tmp [B,128] (fused path only)
// First 8192 BYTES zeroed via hipMemsetAsync before score_k.
#define WS_STATS 256
#define WS_LIST  2048
#define WS_TMP   1048576   // float offset (4 MB byte offset)
#define WS_NEED  ((size_t)(WS_TMP + B_SZ * O_DIM) * 4)

// ---------------- K1: encoder + scorer + UCB + top2 + list build (f64) ----------------
// Round-13 proven config: 16 rows/block, 4 rows/wave, f32-staged x.
__global__ __launch_bounds__(256) void score_k(
    const float* __restrict__ x,
    const float* __restrict__ W1, const float* __restrict__ b1,
    const float* __restrict__ W2, const float* __restrict__ b2,
    const float* __restrict__ S1, const float* __restrict__ sb1,
    const float* __restrict__ S2, const float* __restrict__ sb2,
    const float* __restrict__ er, const int* __restrict__ pulls,
    const int* __restrict__ tsel,
    float* __restrict__ out, int* __restrict__ wsi)
{
    __shared__ float  xs[16][D_DIM];   // 16 KB
    __shared__ double hs[16][H1];      // 8 KB
    __shared__ double cs[16][CTXW];    // 4 KB
    __shared__ double tss[16][CTXW];   // 4 KB
    __shared__ double ucb[16][E_NUM];  // 1 KB
    __shared__ int    se[32];

    const int t = threadIdx.x, lane = t & 63, wv = t >> 6;
    const int row0 = blockIdx.x * 16;

    const float4* xsrc = (const float4*)(x + (size_t)row0 * D_DIM);
    #pragma unroll
    for (int i = 0; i < 4; ++i)
        ((float4*)xs)[t + i * 256] = xsrc[t + i * 256];
    __syncthreads();

    // ---- h = relu(x@W1+b1): lane = unit, 4 rows per wave, 2 accs/row ----
    const int rb = wv * 4;
    {
        double a00 = (double)b1[lane], a01 = 0.0;
        double a10 = a00, a11 = 0.0;
        double a20 = a00, a21 = 0.0;
        double a30 = a00, a31 = 0.0;
        #pragma unroll 4
        for (int d = 0; d < D_DIM; d += 2) {
            float2 p0 = *(const float2*)&xs[rb + 0][d];
            float2 p1 = *(const float2*)&xs[rb + 1][d];
            float2 p2 = *(const float2*)&xs[rb + 2][d];
            float2 p3 = *(const float2*)&xs[rb + 3][d];
            double wa = (double)W1[d * H1 + lane];
            double wb = (double)W1[(d + 1) * H1 + lane];
            a00 = fma((double)p0.x, wa, a00); a01 = fma((double)p0.y, wb, a01);
            a10 = fma((double)p1.x, wa, a10); a11 = fma((double)p1.y, wb, a11);
            a20 = fma((double)p2.x, wa, a20); a21 = fma((double)p2.y, wb, a21);
            a30 = fma((double)p3.x, wa, a30); a31 = fma((double)p3.y, wb, a31);
        }
        double h0 = a00 + a01, h1 = a10 + a11, h2 = a20 + a21, h3 = a30 + a31;
        hs[rb + 0][lane] = h0 > 0.0 ? h0 : 0.0;
        hs[rb + 1][lane] = h1 > 0.0 ? h1 : 0.0;
        hs[rb + 2][lane] = h2 > 0.0 ? h2 : 0.0;
        hs[rb + 3][lane] = h3 > 0.0 ? h3 : 0.0;
    }
    __syncthreads();

    // ---- context = tanh(h@W2+b2) ----
    {
        const int unit = lane & 31, half = lane >> 5;
        const int ra = rb + half * 2;
        double c0 = (double)b2[unit], c1 = c0;
        #pragma unroll 4
        for (int k = 0; k < H1; ++k) {
            double w2v = (double)W2[k * CTXW + unit];
            c0 = fma(hs[ra][k], w2v, c0);
            c1 = fma(hs[ra + 1][k], w2v, c1);
        }
        cs[ra][unit] = tanh(c0);
        cs[ra + 1][unit] = tanh(c1);
    }
    __syncthreads();

    // ---- tmid = relu(context@S1+sb1) ----
    {
        const int unit = lane & 31, half = lane >> 5;
        const int ra = rb + half * 2;
        double a0 = (double)sb1[unit], a1 = a0;
        #pragma unroll 4
        for (int k = 0; k < CTXW; ++k) {
            double s1v = (double)S1[k * CTXW + unit];
            a0 = fma(cs[ra][k], s1v, a0);
            a1 = fma(cs[ra + 1][k], s1v, a1);
        }
        tss[ra][unit]     = a0 > 0.0 ? a0 : 0.0;
        tss[ra + 1][unit] = a1 > 0.0 ? a1 : 0.0;
    }
    __syncthreads();

    // ---- scores + UCB ----
    if (lane < 32) {
        const int e = lane & 7, r = rb + (lane >> 3);
        double a = (double)sb2[e];
        #pragma unroll 4
        for (int k = 0; k < CTXW; ++k)
            a = fma(tss[r][k], (double)S2[k * E_NUM + e], a);
        double pf = (double)pulls[e];
        double sp = pf < 1.0 ? 1.0 : pf;
        double explo = 0.1 * sqrt(log((double)(*tsel)) / sp);
        double avg = pf > 0.0 ? (double)er[e] / sp : 0.0;
        ucb[r][e] = a + avg + explo;
    }
    __syncthreads();

    // ---- top2 + softmax + emit ----
    if (t < 16) {
        double u[E_NUM];
        #pragma unroll
        for (int e = 0; e < E_NUM; ++e) u[e] = ucb[t][e];
        int i0 = 0; double v0 = u[0];
        #pragma unroll
        for (int e = 1; e < E_NUM; ++e) if (u[e] > v0) { v0 = u[e]; i0 = e; }
        int i1 = -1; double v1 = -1.0e300;
        #pragma unroll
        for (int e = 0; e < E_NUM; ++e) {
            if (e == i0) continue;
            if (u[e] > v1) { v1 = u[e]; i1 = e; }
        }
        double exd = exp(v1 - v0);
        double w0 = 1.0 / (1.0 + exd), w1 = exd / (1.0 + exd);
        int row = row0 + t;
        out[OFF_RW  + row * 2]     = (float)w0;
        out[OFF_RW  + row * 2 + 1] = (float)w1;
        out[OFF_IDX + row * 2]     = (float)i0;
        out[OFF_IDX + row * 2 + 1] = (float)i1;
        se[t * 2]     = i0;
        se[t * 2 + 1] = i1;
    }
    __syncthreads();

    // ---- block-aggregated list append: 16 threads, one per (expert, slot) ----
    if (t < 16) {
        const int e = t & 7, slot = t >> 3;
        int cntl = 0;
        for (int j = slot; j < 32; j += 2) cntl += (se[j] == e);
        if (cntl) {
            int base = atomicAdd(&wsi[slot * 8 + e], cntl);
            int k = 0;
            if (slot == 0) {
                for (int j = 0; j < 32; j += 2)
                    if (se[j] == e)
                        wsi[WS_LIST + e * B_SZ + base + (k++)] = row0 + (j >> 1);
            } else {
                for (int j = 1; j < 32; j += 2)
                    if (se[j] == e)
                        wsi[WS_LIST + e * B_SZ + (B_SZ - 1 - base - (k++))] = row0 + (j >> 1);
            }
        }
    }
}

// ---------------- K2: grouped expert GEMM, reg-staged pipelined ----------------
// FUSED=1: one launch, slot1 -> tmp (plain store). FUSED=0: per-slot, slot1 RMWs out.
template <int FUSED, int SLOTP>
__global__ __launch_bounds__(256) void expert_k(
    const float* __restrict__ x, const float* __restrict__ tgt,
    const float* __restrict__ We, const float* __restrict__ be,
    float* out, int* __restrict__ wsi, float* __restrict__ wsf,
    float* __restrict__ tmp)
{
    const int slot = FUSED ? (int)(blockIdx.x >> 12) : SLOTP;
    const int e = (blockIdx.x >> 9) & 7, chunk = blockIdx.x & 511;
    const int cnt = wsi[slot * 8 + e];
    const int base = chunk * 32;
    if (base >= cnt) return;

    __shared__ float xsl[32][68];      // 8.7 KB
    __shared__ float wes[64][O_DIM];   // 32 KB
    __shared__ int   rowid[32];
    __shared__ float wsl[32];
    __shared__ float be_sh[O_DIM];

    const int t = threadIdx.x;
    if (t < 32) {
        bool ok = (base + t) < cnt;
        int row = -1;
        if (ok) {
            int idx = (slot == 0) ? (base + t) : (B_SZ - 1 - (base + t));
            row = wsi[WS_LIST + e * B_SZ + idx];
        }
        rowid[t] = row;
        wsl[t]   = ok ? out[OFF_RW + row * 2 + slot] : 0.f;
    }
    if (t < O_DIM) be_sh[t] = be[e * O_DIM + t];
    __syncthreads();   // rowid ready for loop-invariant x pointer

    const int xr_ = t >> 3, xseg = t & 7;
    const int rrow = rowid[xr_] < 0 ? 0 : rowid[xr_];
    const float*  xbase  = x + (size_t)rrow * D_DIM + xseg * 8;
    const float4* wbase4 = (const float4*)(We + (size_t)e * D_DIM * O_DIM);

    // register-staged k0=0 tile
    float4 rw0 = wbase4[t],        rw1 = wbase4[t + 256],
           rw2 = wbase4[t + 512],  rw3 = wbase4[t + 768],
           rw4 = wbase4[t + 1024], rw5 = wbase4[t + 1280],
           rw6 = wbase4[t + 1536], rw7 = wbase4[t + 1792];
    float4 rxa = *(const float4*)(xbase), rxb = *(const float4*)(xbase + 4);

    float acc[4][4];
    #pragma unroll
    for (int r = 0; r < 4; ++r)
        #pragma unroll
        for (int j = 0; j < 4; ++j) acc[r][j] = 0.f;

    const int tx = t & 31, ty = t >> 5;
    const int o4 = tx * 4;

    for (int k0 = 0; k0 < 4; ++k0) {
        if (k0) __syncthreads();               // prev compute finished
        ((float4*)wes)[t]        = rw0;  ((float4*)wes)[t + 256]  = rw1;
        ((float4*)wes)[t + 512]  = rw2;  ((float4*)wes)[t + 768]  = rw3;
        ((float4*)wes)[t + 1024] = rw4;  ((float4*)wes)[t + 1280] = rw5;
        ((float4*)wes)[t + 1536] = rw6;  ((float4*)wes)[t + 1792] = rw7;
        *(float4*)&xsl[xr_][xseg * 8]     = rxa;
        *(float4*)&xsl[xr_][xseg * 8 + 4] = rxb;
        __syncthreads();
        if (k0 < 3) {                          // prefetch next tile (hides under compute)
            const float4* wn = wbase4 + (k0 + 1) * 2048;
            rw0 = wn[t];        rw1 = wn[t + 256];
            rw2 = wn[t + 512];  rw3 = wn[t + 768];
            rw4 = wn[t + 1024]; rw5 = wn[t + 1280];
            rw6 = wn[t + 1536]; rw7 = wn[t + 1792];
            const float* xn = xbase + (k0 + 1) * 64;
            rxa = *(const float4*)xn; rxb = *(const float4*)(xn + 4);
        }
        #pragma unroll 4
        for (int kq = 0; kq < 16; ++kq) {
            float4 w0 = *(float4*)&wes[kq * 4 + 0][o4];
            float4 w1 = *(float4*)&wes[kq * 4 + 1][o4];
            float4 w2 = *(float4*)&wes[kq * 4 + 2][o4];
            float4 w3 = *(float4*)&wes[kq * 4 + 3][o4];
            #pragma unroll
            for (int r = 0; r < 4; ++r) {
                float4 xv = *(float4*)&xsl[ty * 4 + r][kq * 4];
                acc[r][0] = fmaf(xv.x, w0.x, acc[r][0]);
                acc[r][1] = fmaf(xv.x, w0.y, acc[r][1]);
                acc[r][2] = fmaf(xv.x, w0.z, acc[r][2]);
                acc[r][3] = fmaf(xv.x, w0.w, acc[r][3]);
                acc[r][0] = fmaf(xv.y, w1.x, acc[r][0]);
                acc[r][1] = fmaf(xv.y, w1.y, acc[r][1]);
                acc[r][2] = fmaf(xv.y, w1.z, acc[r][2]);
                acc[r][3] = fmaf(xv.y, w1.w, acc[r][3]);
                acc[r][0] = fmaf(xv.z, w2.x, acc[r][0]);
                acc[r][1] = fmaf(xv.z, w2.y, acc[r][1]);
                acc[r][2] = fmaf(xv.z, w2.z, acc[r][2]);
                acc[r][3] = fmaf(xv.z, w2.w, acc[r][3]);
                acc[r][0] = fmaf(xv.w, w3.x, acc[r][0]);
                acc[r][1] = fmaf(xv.w, w3.y, acc[r][1]);
                acc[r][2] = fmaf(xv.w, w3.z, acc[r][2]);
                acc[r][3] = fmaf(xv.w, w3.w, acc[r][3]);
            }
        }
    }

    float cntl = 0.f, rsl = 0.f, wsuml = 0.f;
    #pragma unroll
    for (int r = 0; r < 4; ++r) {
        int li = ty * 4 + r;
        int row = rowid[li];
        bool valid = row >= 0;
        float w = wsl[li];
        float4 tg = make_float4(0.f, 0.f, 0.f, 0.f);
        if (valid) tg = *(const float4*)(tgt + (size_t)row * O_DIM + o4);
        float cf0 = acc[r][0] + be_sh[o4 + 0];
        float cf1 = acc[r][1] + be_sh[o4 + 1];
        float cf2 = acc[r][2] + be_sh[o4 + 2];
        float cf3 = acc[r][3] + be_sh[o4 + 3];
        float d0 = cf0 - tg.x, d1 = cf1 - tg.y, d2 = cf2 - tg.z, d3 = cf3 - tg.w;
        float lpr = d0 * d0 + d1 * d1 + d2 * d2 + d3 * d3;
        if (valid) {
            if (FUSED) {
                float* pr = (slot == 0 ? out : tmp) + (size_t)row * O_DIM + o4;
                *(float4*)pr = make_float4(w * cf0, w * cf1, w * cf2, w * cf3);
            } else {
                float* pr = out + (size_t)row * O_DIM + o4;
                if (SLOTP == 0) {
                    *(float4*)pr = make_float4(w * cf0, w * cf1, w * cf2, w * cf3);
                } else {
                    float4 p = *(const float4*)pr;
                    p.x += w * cf0; p.y += w * cf1; p.z += w * cf2; p.w += w * cf3;
                    *(float4*)pr = p;
                }
            }
        }
        #pragma unroll
        for (int off = 1; off < 32; off <<= 1)
            lpr += __shfl_xor(lpr, off, 64);
        if (tx == 0 && valid) {
            cntl += 1.f;
            rsl  += -(lpr * (1.0f / 128.0f));
            wsuml += w;
        }
    }
    if (tx == 0) {
        int cp = WS_STATS + (blockIdx.x & 63) * 24;
        if (cntl > 0.f) {
            atomicAdd(&wsf[cp + e], cntl);
            atomicAdd(&wsf[cp + 8 + e], rsl);
            atomicAdd(&wsf[cp + 16 + e], wsuml);
        }
    }
}

// ---------------- combine (blocks 0..2047) + finalize stats (block 2048) ----------------
__device__ __forceinline__ void final_stats(const float* er, const float* ema,
                                            const int* pulls, const float* wsf,
                                            float* out)
{
    int e = threadIdx.x;
    if (e < E_NUM) {
        double c = 0.0, rs = 0.0, wsum = 0.0;
        for (int cp = 0; cp < 64; ++cp) {
            c    += (double)wsf[WS_STATS + cp * 24 + e];
            rs   += (double)wsf[WS_STATS + cp * 24 + 8 + e];
            wsum += (double)wsf[WS_STATS + cp * 24 + 16 + e];
        }
        double pf = (double)pulls[e];
        double npl = pf + c;
        double ntr = (double)er[e] + rs;
        double sp = npl < 1.0 ? 1.0 : npl;
        double navg = npl > 0.0 ? ntr / sp : 0.0;
        double prob = wsum / (double)B_SZ;
        double nema = 0.99 * (double)ema[e] + 0.01 * prob;
        out[OFF_NP + e] = (float)npl;
        out[OFF_NA + e] = (float)navg;
        out[OFF_NE + e] = (float)nema;
    }
}

__global__ __launch_bounds__(256) void combine_final_k(
    float* out, const float* __restrict__ tmp,
    const float* __restrict__ er, const float* __restrict__ ema,
    const int* __restrict__ pulls, const float* __restrict__ wsf)
{
    if (blockIdx.x < 2048) {
        int i = blockIdx.x * 256 + threadIdx.x;
        float4 p = ((const float4*)out)[i];
        float4 q = ((const float4*)tmp)[i];
        p.x += q.x; p.y += q.y; p.z += q.z; p.w += q.w;
        ((float4*)out)[i] = p;
    } else {
        final_stats(er, ema, pulls, wsf, out);
    }
}

__global__ void final_k(const float* __restrict__ er,
                        const float* __restrict__ ema,
                        const int* __restrict__ pulls,
                        const float* __restrict__ wsf,
                        float* __restrict__ out)
{
    final_stats(er, ema, pulls, wsf, out);
}

extern "C" void kernel_launch(void* const* d_in, const int* in_sizes, int n_in,
                              void* d_out, int out_size, void* d_ws, size_t ws_size,
                              hipStream_t stream) {
    const float* x    = (const float*)d_in[0];
    const float* tgt  = (const float*)d_in[1];
    const float* W1   = (const float*)d_in[2];
    const float* b1   = (const float*)d_in[3];
    const float* W2   = (const float*)d_in[4];
    const float* b2   = (const float*)d_in[5];
    const float* S1   = (const float*)d_in[6];
    const float* sb1  = (const float*)d_in[7];
    const float* S2   = (const float*)d_in[8];
    const float* sb2  = (const float*)d_in[9];
    const float* We   = (const float*)d_in[10];
    const float* be   = (const float*)d_in[11];
    const float* erw  = (const float*)d_in[12];
    const float* ema  = (const float*)d_in[13];
    const int*   pulls = (const int*)d_in[14];
    const int*   tsel  = (const int*)d_in[15];
    float* out = (float*)d_out;
    float* wsf = (float*)d_ws;
    int*   wsi = (int*)d_ws;
    float* tmp = wsf + WS_TMP;

    hipMemsetAsync(d_ws, 0, 8192, stream);
    score_k<<<B_SZ / 16, 256, 0, stream>>>(
        x, W1, b1, W2, b2, S1, sb1, S2, sb2, erw, pulls, tsel, out, wsi);
    if (ws_size >= WS_NEED) {
        expert_k<1, 0><<<2 * E_NUM * 512, 256, 0, stream>>>(
            x, tgt, We, be, out, wsi, wsf, tmp);
        combine_final_k<<<2049, 256, 0, stream>>>(out, tmp, erw, ema, pulls, wsf);
    } else {
        expert_k<0, 0><<<E_NUM * 512, 256, 0, stream>>>(
            x, tgt, We, be, out, wsi, wsf, tmp);
        expert_k<0, 1><<<E_NUM * 512, 256, 0, stream>>>(
            x, tgt, We, be, out, wsi, wsf, tmp);
        final_k<<<1, 64, 0, stream>>>(erw, ema, pulls, wsf, out);
    }
}